// Round 2
// baseline (6478.362 us; speedup 1.0000x reference)
//
#include <hip/hip_runtime.h>
#include <math.h>

constexpr int NT = 100000;
constexpr int NJ = 300000;
constexpr int E_TJ = 1000000, E_JT = 1000000, E_JJ = 2000000;
constexpr float SP_BIAS = 0.5413248546129181f;  // log(expm1(1.0))

// ---------------- utility ----------------
__global__ void k_zero(int* __restrict__ p, int n) {
    int i = blockIdx.x * 256 + threadIdx.x;
    if (i < n) p[i] = 0;
}

// ---------------- CSR build ----------------
__global__ void k_count(const int* __restrict__ dst, int E, int* __restrict__ deg) {
    int e = blockIdx.x * blockDim.x + threadIdx.x;
    if (e < E) atomicAdd(&deg[dst[e]], 1);
}

__global__ __launch_bounds__(1024) void k_bsum(const int* __restrict__ deg, int n,
                                               int* __restrict__ bsum) {
    __shared__ int s[1024];
    int i = blockIdx.x * 1024 + threadIdx.x;
    s[threadIdx.x] = (i < n) ? deg[i] : 0;
    __syncthreads();
    for (int d = 512; d > 0; d >>= 1) {
        if (threadIdx.x < d) s[threadIdx.x] += s[threadIdx.x + d];
        __syncthreads();
    }
    if (threadIdx.x == 0) bsum[blockIdx.x] = s[0];
}

__global__ void k_scan_bsum(int* bsum, int nb) {
    if (threadIdx.x == 0 && blockIdx.x == 0) {
        int run = 0;
        for (int b = 0; b < nb; ++b) { int t = bsum[b]; bsum[b] = run; run += t; }
    }
}

__global__ __launch_bounds__(1024) void k_scan_final(const int* __restrict__ deg, int n,
                                                     const int* __restrict__ bsum,
                                                     int* __restrict__ off,
                                                     int* __restrict__ cur) {
    __shared__ int s[1024];
    int t = threadIdx.x;
    int i = blockIdx.x * 1024 + t;
    int v = (i < n) ? deg[i] : 0;
    s[t] = v;
    __syncthreads();
    for (int d = 1; d < 1024; d <<= 1) {
        int x = (t >= d) ? s[t - d] : 0;
        __syncthreads();
        s[t] += x;
        __syncthreads();
    }
    int incl = s[t];
    int base = bsum[blockIdx.x];
    if (i < n) {
        int excl = base + incl - v;
        off[i] = excl;
        cur[i] = excl;
        if (i == n - 1) off[n] = base + incl;
    }
}

__global__ void k_fill(const int* __restrict__ src, const int* __restrict__ dst, int E,
                       int* __restrict__ cur, int* __restrict__ out_src) {
    int e = blockIdx.x * blockDim.x + threadIdx.x;
    if (e < E) {
        int p = atomicAdd(&cur[dst[e]], 1);
        out_src[p] = src[e];
    }
}

// ---------------- dense ops ----------------
// h = x @ w + b   (x: n x 32, w: 32 x 64) — one wave per node, lane = out feature
__global__ __launch_bounds__(256) void k_in_linear(const float* __restrict__ x,
        const float* __restrict__ w, const float* __restrict__ b,
        float* __restrict__ h, int n) {
    __shared__ float ws_[32 * 64];
    for (int i = threadIdx.x; i < 32 * 64; i += 256) ws_[i] = w[i];
    __syncthreads();
    int wave = (blockIdx.x * 256 + threadIdx.x) >> 6;
    int lane = threadIdx.x & 63;
    int nwaves = gridDim.x * 4;
    for (int i = wave; i < n; i += nwaves) {
        float xv = (lane < 32) ? x[(size_t)i * 32 + lane] : 0.f;
        float acc = b[lane];
        #pragma unroll
        for (int k = 0; k < 32; ++k)
            acc += __shfl(xv, k) * ws_[k * 64 + lane];
        h[(size_t)i * 64 + lane] = acc;
    }
}

__global__ void k_addw(const float* __restrict__ a, const float* __restrict__ b,
                       float* __restrict__ c) {
    int i = blockIdx.x * 256 + threadIdx.x;
    if (i < 64 * 64) c[i] = a[i] + b[i];
}

// torso dst: hout = tanh( segsum(h_src)@rel_w + rel_b + hself@root_w )
__global__ __launch_bounds__(256) void k_agg_t(const float* __restrict__ a,
        const float* __restrict__ hself, float* __restrict__ hout,
        const int* __restrict__ off, const int* __restrict__ srcs,
        const float* __restrict__ rel_w, const float* __restrict__ rel_b,
        const float* __restrict__ root_w, int n) {
    __shared__ float wr_[64 * 64];
    __shared__ float wo_[64 * 64];
    for (int i = threadIdx.x; i < 64 * 64; i += 256) { wr_[i] = rel_w[i]; wo_[i] = root_w[i]; }
    __syncthreads();
    int wave = (blockIdx.x * 256 + threadIdx.x) >> 6;
    int lane = threadIdx.x & 63;
    int nwaves = gridDim.x * 4;
    for (int i = wave; i < n; i += nwaves) {
        float hv = hself[(size_t)i * 64 + lane];
        float m = 0.f;
        int e = off[i], s1 = off[i + 1];
        for (; e + 4 <= s1; e += 4) {
            int i0 = srcs[e], i1 = srcs[e + 1], i2 = srcs[e + 2], i3 = srcs[e + 3];
            float v0 = a[(size_t)i0 * 64 + lane];
            float v1 = a[(size_t)i1 * 64 + lane];
            float v2 = a[(size_t)i2 * 64 + lane];
            float v3 = a[(size_t)i3 * 64 + lane];
            m += (v0 + v1) + (v2 + v3);
        }
        for (; e < s1; ++e) m += a[(size_t)srcs[e] * 64 + lane];
        float r = rel_b[lane];
        #pragma unroll
        for (int k = 0; k < 64; ++k) {
            r += __shfl(m, k) * wr_[k * 64 + lane];
            r += __shfl(hv, k) * wo_[k * 64 + lane];
        }
        hout[(size_t)i * 64 + lane] = tanhf(r);
    }
}

// joint dst: two edge types (tj from torso feats, jj from joint feats), summed roots
__global__ __launch_bounds__(256) void k_agg_j(const float* __restrict__ aT,
        const float* __restrict__ aJ, const float* __restrict__ hself,
        float* __restrict__ hout,
        const int* __restrict__ off1, const int* __restrict__ srcs1,
        const int* __restrict__ off2, const int* __restrict__ srcs2,
        const float* __restrict__ w1g, const float* __restrict__ b1,
        const float* __restrict__ w2g, const float* __restrict__ b2,
        const float* __restrict__ wcomb, int n) {
    __shared__ float w1_[64 * 64];
    __shared__ float w2_[64 * 64];
    __shared__ float w3_[64 * 64];
    for (int i = threadIdx.x; i < 64 * 64; i += 256) {
        w1_[i] = w1g[i]; w2_[i] = w2g[i]; w3_[i] = wcomb[i];
    }
    __syncthreads();
    int wave = (blockIdx.x * 256 + threadIdx.x) >> 6;
    int lane = threadIdx.x & 63;
    int nwaves = gridDim.x * 4;
    for (int i = wave; i < n; i += nwaves) {
        float hv = hself[(size_t)i * 64 + lane];
        float m1 = 0.f;
        int e = off1[i], s1 = off1[i + 1];
        for (; e + 4 <= s1; e += 4) {
            int i0 = srcs1[e], i1 = srcs1[e + 1], i2 = srcs1[e + 2], i3 = srcs1[e + 3];
            float v0 = aT[(size_t)i0 * 64 + lane];
            float v1 = aT[(size_t)i1 * 64 + lane];
            float v2 = aT[(size_t)i2 * 64 + lane];
            float v3 = aT[(size_t)i3 * 64 + lane];
            m1 += (v0 + v1) + (v2 + v3);
        }
        for (; e < s1; ++e) m1 += aT[(size_t)srcs1[e] * 64 + lane];
        float m2 = 0.f;
        e = off2[i]; s1 = off2[i + 1];
        for (; e + 4 <= s1; e += 4) {
            int i0 = srcs2[e], i1 = srcs2[e + 1], i2 = srcs2[e + 2], i3 = srcs2[e + 3];
            float v0 = aJ[(size_t)i0 * 64 + lane];
            float v1 = aJ[(size_t)i1 * 64 + lane];
            float v2 = aJ[(size_t)i2 * 64 + lane];
            float v3 = aJ[(size_t)i3 * 64 + lane];
            m2 += (v0 + v1) + (v2 + v3);
        }
        for (; e < s1; ++e) m2 += aJ[(size_t)srcs2[e] * 64 + lane];
        float r = b1[lane] + b2[lane];
        #pragma unroll
        for (int k = 0; k < 64; ++k) {
            r += __shfl(m1, k) * w1_[k * 64 + lane];
            r += __shfl(m2, k) * w2_[k * 64 + lane];
            r += __shfl(hv, k) * w3_[k * 64 + lane];
        }
        hout[(size_t)i * 64 + lane] = tanhf(r);
    }
}

// o = tanh(h @ w3 + b3); loc = o[:8], scale = softplus(o[8:] + SP_BIAS)
__global__ __launch_bounds__(256) void k_out(const float* __restrict__ h,
        const float* __restrict__ w3, const float* __restrict__ b3,
        float* __restrict__ loc, float* __restrict__ scale, int n) {
    __shared__ float ws_[64 * 16];
    for (int i = threadIdx.x; i < 64 * 16; i += 256) ws_[i] = w3[i];
    __syncthreads();
    int wave = (blockIdx.x * 256 + threadIdx.x) >> 6;
    int lane = threadIdx.x & 63;
    int nwaves = gridDim.x * 4;
    for (int i = wave; i < n; i += nwaves) {
        float hv = h[(size_t)i * 64 + lane];
        float acc = (lane < 16) ? b3[lane] : 0.f;
        #pragma unroll
        for (int k = 0; k < 64; ++k) {
            float hk = __shfl(hv, k);
            if (lane < 16) acc += hk * ws_[k * 16 + lane];
        }
        if (lane < 16) {
            float v = tanhf(acc);
            if (lane < 8) {
                loc[(size_t)i * 8 + lane] = v;
            } else {
                float x = v + SP_BIAS;
                float sp = (x > 20.f) ? x : log1pf(expf(x));
                scale[(size_t)i * 8 + (lane - 8)] = sp;
            }
        }
    }
}

// ---------------- launch ----------------
extern "C" void kernel_launch(void* const* d_in, const int* in_sizes, int n_in,
                              void* d_out, int out_size, void* d_ws, size_t ws_size,
                              hipStream_t stream) {
    const float* x_t  = (const float*)d_in[0];
    const float* x_j  = (const float*)d_in[1];
    const int*   ei_tj = (const int*)d_in[2];
    const int*   ei_jt = (const int*)d_in[3];
    const int*   ei_jj = (const int*)d_in[4];
    const float* w0_t = (const float*)d_in[5];
    const float* b0_t = (const float*)d_in[6];
    const float* w0_j = (const float*)d_in[7];
    const float* b0_j = (const float*)d_in[8];
    const float* w3_t = (const float*)d_in[27];
    const float* b3_t = (const float*)d_in[28];
    const float* w3_j = (const float*)d_in[29];
    const float* b3_j = (const float*)d_in[30];

    // workspace layout (floats then ints)
    float* fws   = (float*)d_ws;
    float* hA_t  = fws;                              // NT*64
    float* hA_j  = hA_t + (size_t)NT * 64;           // NJ*64
    float* hB_t  = hA_j + (size_t)NJ * 64;           // NT*64
    float* hB_j  = hB_t + (size_t)NT * 64;           // NJ*64
    float* wcomb = hB_j + (size_t)NJ * 64;           // 64*64
    int* iws    = (int*)(wcomb + 64 * 64);
    int* off_jt = iws;                               // NT+1
    int* cur_jt = off_jt + NT + 1;                   // NT
    int* off_tj = cur_jt + NT;                       // NJ+1
    int* cur_tj = off_tj + NJ + 1;                   // NJ
    int* off_jj = cur_tj + NJ;                       // NJ+1
    int* cur_jj = off_jj + NJ + 1;                   // NJ
    int* src_jt = cur_jj + NJ;                       // E_JT
    int* src_tj = src_jt + E_JT;                     // E_TJ
    int* src_jj = src_tj + E_TJ;                     // E_JJ
    int* bsum   = src_jj + E_JJ;                     // 1024

    size_t required = (size_t)(src_jj + E_JJ + 1024 - iws) * 4
                    + (size_t)(iws - (int*)d_ws) * 4;
    if (ws_size < required) return;  // leaves d_out poisoned -> distinguishable failure

    // ---- CSR build (identical for both layers; rebuilt every call) ----
    k_zero<<<(NT + 255) / 256, 256, 0, stream>>>(cur_jt, NT);
    k_zero<<<(NJ + 255) / 256, 256, 0, stream>>>(cur_tj, NJ);
    k_zero<<<(NJ + 255) / 256, 256, 0, stream>>>(cur_jj, NJ);
    k_count<<<(E_JT + 255) / 256, 256, 0, stream>>>(ei_jt + E_JT, E_JT, cur_jt);
    k_count<<<(E_TJ + 255) / 256, 256, 0, stream>>>(ei_tj + E_TJ, E_TJ, cur_tj);
    k_count<<<(E_JJ + 255) / 256, 256, 0, stream>>>(ei_jj + E_JJ, E_JJ, cur_jj);

    auto scan = [&](int* cur, int* off, int n) {
        int nb = (n + 1023) / 1024;
        k_bsum<<<nb, 1024, 0, stream>>>(cur, n, bsum);
        k_scan_bsum<<<1, 64, 0, stream>>>(bsum, nb);
        k_scan_final<<<nb, 1024, 0, stream>>>(cur, n, bsum, off, cur);
    };
    scan(cur_jt, off_jt, NT);
    scan(cur_tj, off_tj, NJ);
    scan(cur_jj, off_jj, NJ);

    k_fill<<<(E_JT + 255) / 256, 256, 0, stream>>>(ei_jt, ei_jt + E_JT, E_JT, cur_jt, src_jt);
    k_fill<<<(E_TJ + 255) / 256, 256, 0, stream>>>(ei_tj, ei_tj + E_TJ, E_TJ, cur_tj, src_tj);
    k_fill<<<(E_JJ + 255) / 256, 256, 0, stream>>>(ei_jj, ei_jj + E_JJ, E_JJ, cur_jj, src_jj);

    // ---- input linears (into set A) ----
    k_in_linear<<<2048, 256, 0, stream>>>(x_t, w0_t, b0_t, hA_t, NT);
    k_in_linear<<<2048, 256, 0, stream>>>(x_j, w0_j, b0_j, hA_j, NJ);

    // ---- 2 hetero GraphConv layers, ping-pong A->B->A ----
    float* ht_in = hA_t; float* hj_in = hA_j;
    float* ht_out = hB_t; float* hj_out = hB_j;
    for (int l = 0; l < 2; ++l) {
        const float* tj_rel_w  = (const float*)d_in[9 + l * 9 + 0];
        const float* tj_rel_b  = (const float*)d_in[9 + l * 9 + 1];
        const float* tj_root_w = (const float*)d_in[9 + l * 9 + 2];
        const float* jt_rel_w  = (const float*)d_in[9 + l * 9 + 3];
        const float* jt_rel_b  = (const float*)d_in[9 + l * 9 + 4];
        const float* jt_root_w = (const float*)d_in[9 + l * 9 + 5];
        const float* jj_rel_w  = (const float*)d_in[9 + l * 9 + 6];
        const float* jj_rel_b  = (const float*)d_in[9 + l * 9 + 7];
        const float* jj_root_w = (const float*)d_in[9 + l * 9 + 8];

        k_addw<<<16, 256, 0, stream>>>(tj_root_w, jj_root_w, wcomb);
        // torso: gathers joint feats over jt edges (32KB LDS -> 5 blk/CU -> 1280)
        k_agg_t<<<1280, 256, 0, stream>>>(hj_in, ht_in, ht_out,
                                          off_jt, src_jt, jt_rel_w, jt_rel_b, jt_root_w, NT);
        // joint: gathers torso (tj) + joint (jj) feats (48KB LDS -> 3 blk/CU -> 768)
        k_agg_j<<<768, 256, 0, stream>>>(ht_in, hj_in, hj_in, hj_out,
                                         off_tj, src_tj, off_jj, src_jj,
                                         tj_rel_w, tj_rel_b, jj_rel_w, jj_rel_b, wcomb, NJ);
        float* t;
        t = ht_in; ht_in = ht_out; ht_out = t;
        t = hj_in; hj_in = hj_out; hj_out = t;
    }

    // ---- output heads (h now in ht_in/hj_in == set A) ----
    float* out = (float*)d_out;
    k_out<<<2048, 256, 0, stream>>>(ht_in, w3_t, b3_t,
                                    out, out + (size_t)NT * 8, NT);
    k_out<<<2048, 256, 0, stream>>>(hj_in, w3_j, b3_j,
                                    out + (size_t)2 * NT * 8,
                                    out + (size_t)2 * NT * 8 + (size_t)NJ * 8, NJ);
}

// Round 3
// 2940.288 us; speedup vs baseline: 2.2033x; 2.2033x over previous
//
#include <hip/hip_runtime.h>
#include <math.h>

constexpr int NT = 100000;
constexpr int NJ = 300000;
constexpr int E_TJ = 1000000, E_JT = 1000000, E_JJ = 2000000;
constexpr float SP_BIAS = 0.5413248546129181f;  // log(expm1(1.0))

// ---------------- utility ----------------
__global__ void k_zero(int* __restrict__ p, int n) {
    int i = blockIdx.x * 256 + threadIdx.x;
    if (i < n) p[i] = 0;
}

// ---------------- CSR build ----------------
__global__ void k_count(const int* __restrict__ dst, int E, int* __restrict__ deg) {
    int e = blockIdx.x * blockDim.x + threadIdx.x;
    if (e < E) atomicAdd(&deg[dst[e]], 1);
}

__global__ __launch_bounds__(1024) void k_bsum(const int* __restrict__ deg, int n,
                                               int* __restrict__ bsum) {
    __shared__ int s[1024];
    int i = blockIdx.x * 1024 + threadIdx.x;
    s[threadIdx.x] = (i < n) ? deg[i] : 0;
    __syncthreads();
    for (int d = 512; d > 0; d >>= 1) {
        if (threadIdx.x < d) s[threadIdx.x] += s[threadIdx.x + d];
        __syncthreads();
    }
    if (threadIdx.x == 0) bsum[blockIdx.x] = s[0];
}

__global__ void k_scan_bsum(int* bsum, int nb) {
    if (threadIdx.x == 0 && blockIdx.x == 0) {
        int run = 0;
        for (int b = 0; b < nb; ++b) { int t = bsum[b]; bsum[b] = run; run += t; }
    }
}

__global__ __launch_bounds__(1024) void k_scan_final(const int* __restrict__ deg, int n,
                                                     const int* __restrict__ bsum,
                                                     int* __restrict__ off,
                                                     int* __restrict__ cur) {
    __shared__ int s[1024];
    int t = threadIdx.x;
    int i = blockIdx.x * 1024 + t;
    int v = (i < n) ? deg[i] : 0;
    s[t] = v;
    __syncthreads();
    for (int d = 1; d < 1024; d <<= 1) {
        int x = (t >= d) ? s[t - d] : 0;
        __syncthreads();
        s[t] += x;
        __syncthreads();
    }
    int incl = s[t];
    int base = bsum[blockIdx.x];
    if (i < n) {
        int excl = base + incl - v;
        off[i] = excl;
        cur[i] = excl;
        if (i == n - 1) off[n] = base + incl;
    }
}

__global__ void k_fill(const int* __restrict__ src, const int* __restrict__ dst, int E,
                       int* __restrict__ cur, int* __restrict__ out_src, int src_ofs) {
    int e = blockIdx.x * blockDim.x + threadIdx.x;
    if (e < E) {
        int p = atomicAdd(&cur[dst[e]], 1);
        out_src[p] = src[e] + src_ofs;
    }
}

// ---------------- dense ops ----------------
// h = x @ w + b   (x: n x 32) — one wave per node, lane = out feature
__global__ __launch_bounds__(256) void k_in_linear(const float* __restrict__ x,
        const float* __restrict__ w, const float* __restrict__ b,
        float* __restrict__ h, int n) {
    __shared__ float ws_[32 * 64];
    for (int i = threadIdx.x; i < 32 * 64; i += 256) ws_[i] = w[i];
    __syncthreads();
    int wave = (blockIdx.x * 256 + threadIdx.x) >> 6;
    int lane = threadIdx.x & 63;
    int nwaves = gridDim.x * 4;
    for (int i = wave; i < n; i += nwaves) {
        float xv = (lane < 32) ? x[(size_t)i * 32 + lane] : 0.f;
        float acc = b[lane];
        #pragma unroll
        for (int k = 0; k < 32; ++k)
            acc += __shfl(xv, k) * ws_[k * 64 + lane];
        h[(size_t)i * 64 + lane] = acc;
    }
}

__global__ void k_addw(const float* __restrict__ a, const float* __restrict__ b,
                       float* __restrict__ c) {
    int i = blockIdx.x * 256 + threadIdx.x;
    if (i < 64 * 64) c[i] = a[i] + b[i];
}

__global__ void k_addb(const float* __restrict__ a, const float* __restrict__ b,
                       float* __restrict__ c) {
    int i = threadIdx.x;
    if (i < 64) c[i] = a[i] + b[i];
}

// a = h @ w  (64x64), streaming
__global__ __launch_bounds__(256) void k_transform(const float* __restrict__ h,
        const float* __restrict__ w, float* __restrict__ a, int n) {
    __shared__ float ws_[64 * 64];
    for (int i = threadIdx.x; i < 64 * 64; i += 256) ws_[i] = w[i];
    __syncthreads();
    int wave = (blockIdx.x * 256 + threadIdx.x) >> 6;
    int lane = threadIdx.x & 63;
    int nwaves = gridDim.x * 4;
    for (int i = wave; i < n; i += nwaves) {
        float hv = h[(size_t)i * 64 + lane];
        float acc = 0.f;
        #pragma unroll
        for (int k = 0; k < 64; ++k)
            acc += __shfl(hv, k) * ws_[k * 64 + lane];
        a[(size_t)i * 64 + lane] = acc;
    }
}

// h[i] = tanh( sum_{e} a[src_e] + bias + h[i]@root_w )  — in place, a pre-transformed
__global__ __launch_bounds__(256, 4) void k_aggfin(const float* __restrict__ a,
        float* __restrict__ h,
        const int* __restrict__ off, const int* __restrict__ srcs,
        const float* __restrict__ bias, const float* __restrict__ root_w, int n) {
    __shared__ float wo_[64 * 64];
    for (int i = threadIdx.x; i < 64 * 64; i += 256) wo_[i] = root_w[i];
    __syncthreads();
    int wave = (blockIdx.x * 256 + threadIdx.x) >> 6;
    int lane = threadIdx.x & 63;
    int nwaves = gridDim.x * 4;
    for (int i = wave; i < n; i += nwaves) {
        int e0 = off[i], e1 = off[i + 1];
        float acc = 0.f;
        for (int base = e0; base < e1; base += 64) {
            int rem = e1 - base;
            int cnt = rem < 64 ? rem : 64;
            int li = lane < cnt ? lane : cnt - 1;
            int idx = srcs[base + li];          // 64 indices in one coalesced load
            int k = 0;
            for (; k + 8 <= cnt; k += 8) {
                int s0 = __shfl(idx, k),     s1 = __shfl(idx, k + 1);
                int s2 = __shfl(idx, k + 2), s3 = __shfl(idx, k + 3);
                int s4 = __shfl(idx, k + 4), s5 = __shfl(idx, k + 5);
                int s6 = __shfl(idx, k + 6), s7 = __shfl(idx, k + 7);
                float v0 = a[(size_t)s0 * 64 + lane], v1 = a[(size_t)s1 * 64 + lane];
                float v2 = a[(size_t)s2 * 64 + lane], v3 = a[(size_t)s3 * 64 + lane];
                float v4 = a[(size_t)s4 * 64 + lane], v5 = a[(size_t)s5 * 64 + lane];
                float v6 = a[(size_t)s6 * 64 + lane], v7 = a[(size_t)s7 * 64 + lane];
                acc += ((v0 + v1) + (v2 + v3)) + ((v4 + v5) + (v6 + v7));
            }
            for (; k + 4 <= cnt; k += 4) {
                int s0 = __shfl(idx, k),     s1 = __shfl(idx, k + 1);
                int s2 = __shfl(idx, k + 2), s3 = __shfl(idx, k + 3);
                float v0 = a[(size_t)s0 * 64 + lane], v1 = a[(size_t)s1 * 64 + lane];
                float v2 = a[(size_t)s2 * 64 + lane], v3 = a[(size_t)s3 * 64 + lane];
                acc += (v0 + v1) + (v2 + v3);
            }
            for (; k < cnt; ++k)
                acc += a[(size_t)__shfl(idx, k) * 64 + lane];
        }
        float hv = h[(size_t)i * 64 + lane];
        float r = acc + bias[lane];
        #pragma unroll
        for (int k = 0; k < 64; ++k)
            r += __shfl(hv, k) * wo_[k * 64 + lane];
        h[(size_t)i * 64 + lane] = tanhf(r);
    }
}

// o = tanh(h @ w3 + b3); loc = o[:8], scale = softplus(o[8:] + SP_BIAS)
__global__ __launch_bounds__(256) void k_out(const float* __restrict__ h,
        const float* __restrict__ w3, const float* __restrict__ b3,
        float* __restrict__ loc, float* __restrict__ scale, int n) {
    __shared__ float ws_[64 * 16];
    for (int i = threadIdx.x; i < 64 * 16; i += 256) ws_[i] = w3[i];
    __syncthreads();
    int wave = (blockIdx.x * 256 + threadIdx.x) >> 6;
    int lane = threadIdx.x & 63;
    int nwaves = gridDim.x * 4;
    for (int i = wave; i < n; i += nwaves) {
        float hv = h[(size_t)i * 64 + lane];
        float acc = (lane < 16) ? b3[lane] : 0.f;
        #pragma unroll
        for (int k = 0; k < 64; ++k) {
            float hk = __shfl(hv, k);
            if (lane < 16) acc += hk * ws_[k * 16 + lane];
        }
        if (lane < 16) {
            float v = tanhf(acc);
            if (lane < 8) {
                loc[(size_t)i * 8 + lane] = v;
            } else {
                float x = v + SP_BIAS;
                float sp = (x > 20.f) ? x : log1pf(expf(x));
                scale[(size_t)i * 8 + (lane - 8)] = sp;
            }
        }
    }
}

// ---------------- launch ----------------
extern "C" void kernel_launch(void* const* d_in, const int* in_sizes, int n_in,
                              void* d_out, int out_size, void* d_ws, size_t ws_size,
                              hipStream_t stream) {
    const float* x_t  = (const float*)d_in[0];
    const float* x_j  = (const float*)d_in[1];
    const int*   ei_tj = (const int*)d_in[2];
    const int*   ei_jt = (const int*)d_in[3];
    const int*   ei_jj = (const int*)d_in[4];
    const float* w0_t = (const float*)d_in[5];
    const float* b0_t = (const float*)d_in[6];
    const float* w0_j = (const float*)d_in[7];
    const float* b0_j = (const float*)d_in[8];
    const float* w3_t = (const float*)d_in[27];
    const float* b3_t = (const float*)d_in[28];
    const float* w3_j = (const float*)d_in[29];
    const float* b3_j = (const float*)d_in[30];

    // workspace layout: Q and P MUST be contiguous ([Q;P] combined index space)
    float* fws   = (float*)d_ws;
    float* Q     = fws;                              // NT*64 (transformed torso)
    float* P     = Q + (size_t)NT * 64;              // NJ*64 (transformed joint, reused)
    float* h_t   = P + (size_t)NJ * 64;              // NT*64
    float* h_j   = h_t + (size_t)NT * 64;            // NJ*64
    float* wcomb = h_j + (size_t)NJ * 64;            // 64*64
    float* bcomb = wcomb + 64 * 64;                  // 64
    int* iws    = (int*)(bcomb + 64);
    int* off_jt = iws;                               // NT+1
    int* cur_jt = off_jt + NT + 1;                   // NT
    int* off_cj = cur_jt + NT;                       // NJ+1  (combined tj+jj -> joint)
    int* cur_cj = off_cj + NJ + 1;                   // NJ
    int* src_jt = cur_cj + NJ;                       // E_JT
    int* src_cj = src_jt + E_JT;                     // E_TJ + E_JJ
    int* bsum   = src_cj + E_TJ + E_JJ;              // 1024

    size_t required = ((char*)(bsum + 1024)) - ((char*)d_ws);
    if (ws_size < required) return;  // distinguishable failure (output stays poisoned)

    // ---- CSR build (edges identical both layers) ----
    k_zero<<<(NT + 255) / 256, 256, 0, stream>>>(cur_jt, NT);
    k_zero<<<(NJ + 255) / 256, 256, 0, stream>>>(cur_cj, NJ);
    k_count<<<(E_JT + 255) / 256, 256, 0, stream>>>(ei_jt + E_JT, E_JT, cur_jt);
    k_count<<<(E_TJ + 255) / 256, 256, 0, stream>>>(ei_tj + E_TJ, E_TJ, cur_cj);
    k_count<<<(E_JJ + 255) / 256, 256, 0, stream>>>(ei_jj + E_JJ, E_JJ, cur_cj);

    auto scan = [&](int* cur, int* off, int n) {
        int nb = (n + 1023) / 1024;
        k_bsum<<<nb, 1024, 0, stream>>>(cur, n, bsum);
        k_scan_bsum<<<1, 64, 0, stream>>>(bsum, nb);
        k_scan_final<<<nb, 1024, 0, stream>>>(cur, n, bsum, off, cur);
    };
    scan(cur_jt, off_jt, NT);
    scan(cur_cj, off_cj, NJ);

    k_fill<<<(E_JT + 255) / 256, 256, 0, stream>>>(ei_jt, ei_jt + E_JT, E_JT, cur_jt, src_jt, 0);
    // combined joint CSR: tj sources index Q rows [0,NT), jj sources index P rows via +NT
    k_fill<<<(E_TJ + 255) / 256, 256, 0, stream>>>(ei_tj, ei_tj + E_TJ, E_TJ, cur_cj, src_cj, 0);
    k_fill<<<(E_JJ + 255) / 256, 256, 0, stream>>>(ei_jj, ei_jj + E_JJ, E_JJ, cur_cj, src_cj, NT);

    // ---- input linears ----
    k_in_linear<<<2048, 256, 0, stream>>>(x_t, w0_t, b0_t, h_t, NT);
    k_in_linear<<<2048, 256, 0, stream>>>(x_j, w0_j, b0_j, h_j, NJ);

    // ---- 2 hetero GraphConv layers (in-place h updates) ----
    for (int l = 0; l < 2; ++l) {
        const float* tj_rel_w  = (const float*)d_in[9 + l * 9 + 0];
        const float* tj_rel_b  = (const float*)d_in[9 + l * 9 + 1];
        const float* tj_root_w = (const float*)d_in[9 + l * 9 + 2];
        const float* jt_rel_w  = (const float*)d_in[9 + l * 9 + 3];
        const float* jt_rel_b  = (const float*)d_in[9 + l * 9 + 4];
        const float* jt_root_w = (const float*)d_in[9 + l * 9 + 5];
        const float* jj_rel_w  = (const float*)d_in[9 + l * 9 + 6];
        const float* jj_rel_b  = (const float*)d_in[9 + l * 9 + 7];
        const float* jj_root_w = (const float*)d_in[9 + l * 9 + 8];

        k_addw<<<16, 256, 0, stream>>>(tj_root_w, jj_root_w, wcomb);
        k_addb<<<1, 64, 0, stream>>>(tj_rel_b, jj_rel_b, bcomb);

        // transform-first (linearity): Q = h_t @ W_tj (old h_t), P = h_j @ W_jt
        k_transform<<<2048, 256, 0, stream>>>(h_t, tj_rel_w, Q, NT);
        k_transform<<<2048, 256, 0, stream>>>(h_j, jt_rel_w, P, NJ);
        // torso update in place (consumes P)
        k_aggfin<<<2048, 256, 0, stream>>>(P, h_t, off_jt, src_jt, jt_rel_b, jt_root_w, NT);
        // reuse P: P = h_j @ W_jj (h_j still old)
        k_transform<<<2048, 256, 0, stream>>>(h_j, jj_rel_w, P, NJ);
        // joint update in place; combined CSR gathers from contiguous [Q;P]
        k_aggfin<<<2048, 256, 0, stream>>>(Q, h_j, off_cj, src_cj, bcomb, wcomb, NJ);
    }

    // ---- output heads ----
    float* out = (float*)d_out;
    k_out<<<2048, 256, 0, stream>>>(h_t, w3_t, b3_t,
                                    out, out + (size_t)NT * 8, NT);
    k_out<<<2048, 256, 0, stream>>>(h_j, w3_j, b3_j,
                                    out + (size_t)2 * NT * 8,
                                    out + (size_t)2 * NT * 8 + (size_t)NJ * 8, NJ);
}